// Round 11
// baseline (291.481 us; speedup 1.0000x reference)
//
#include <hip/hip_runtime.h>

typedef unsigned short u16;
typedef unsigned int u32;
using f32x4 = __attribute__((ext_vector_type(4))) float;
using f32x16 = __attribute__((ext_vector_type(16))) float;
using u32x4 = __attribute__((ext_vector_type(4))) u32;
typedef u32x4 __attribute__((may_alias)) u32x4a;  // TBAA-safe 16B vector
typedef uint2 __attribute__((may_alias)) uint2a;  // TBAA-safe 8B vector
using bf16x8 = __attribute__((ext_vector_type(8))) __bf16;

#define SEQ 2048  // per batch

// fp32 -> bf16 round-to-nearest-even
__device__ __forceinline__ u16 f2bf(float f) {
  union { float f; u32 u; } c; c.f = f;
  return (u16)((c.u + 0x7fffu + ((c.u >> 16) & 1u)) >> 16);
}
__device__ __forceinline__ float bf2f(u16 h) {
  union { u32 u; float f; } c; c.u = ((u32)h) << 16;
  return c.f;
}
__device__ __forceinline__ bf16x8 ld16(const u16* p) {
  return __builtin_bit_cast(bf16x8, *(const u32x4a*)p);
}
__device__ __forceinline__ f32x4 mfma16(bf16x8 a, bf16x8 b, f32x4 c) {
  return __builtin_amdgcn_mfma_f32_16x16x32_bf16(a, b, c, 0, 0, 0);
}
__device__ __forceinline__ f32x16 mfma32(bf16x8 a, bf16x8 b, f32x16 c) {
  return __builtin_amdgcn_mfma_f32_32x32x16_bf16(a, b, c, 0, 0, 0);
}
// async global->LDS, 16B/lane; LDS dest = wave-uniform base + lane*16
__device__ __forceinline__ void gload_lds16(const u16* g, u16* l) {
  __builtin_amdgcn_global_load_lds(
      (const __attribute__((address_space(1))) void*)g,
      (__attribute__((address_space(3))) void*)l, 16, 0, 0);
}
// pack 2 fp32 -> 1 u32 of 2 bf16 (RNE); no builtin on gfx950
__device__ __forceinline__ u32 cvtpk(float lo, float hi) {
  u32 r;
  asm("v_cvt_pk_bf16_f32 %0, %1, %2" : "=v"(r) : "v"(lo), "v"(hi));
  return r;
}
// new_a = [a.lanes0-31 | b.lanes0-31], new_b = [a.lanes32-63 | b.lanes32-63]
__device__ __forceinline__ void plane32_swap(u32& a, u32& b) {
  asm("v_permlane32_swap_b32 %0, %1" : "+v"(a), "+v"(b));
}
// dtype sniff: bf16 iff exponent bits of x[2i] cluster near 127
__device__ __forceinline__ int detect_flag(const u16* x) {
  int cnt = 0;
  for (int i = 0; i < 32; ++i) {
    const int e = (x[2 * i] >> 7) & 0xFF;
    cnt += (e >= 100 && e <= 140) ? 1 : 0;
  }
  return (cnt >= 20) ? 1 : 0;
}

// ---------------- fused prep: detect + bias cvt + both W transposes -----
// grid 1041 x 256: [0,768) w_qkv 64x64 tiles; [768,1024) w_out tiles;
// [1024,1036) bqf; [1036,1040) bof; 1040 persists flag for cvt_x.
// Each block computes the dtype flag inline (lane 0 + LDS broadcast) --
// removes the 1-block detect kernel that gated the whole device.
__global__ __launch_bounds__(256)
void prep_all(const void* __restrict__ x, const void* __restrict__ w_qkv,
              const void* __restrict__ b_qkv, const void* __restrict__ w_out,
              const void* __restrict__ b_out, u16* __restrict__ wqkvT,
              u16* __restrict__ woutT, float* __restrict__ bqf,
              float* __restrict__ bof, int* __restrict__ flagp) {
  __shared__ int sflag;
  __shared__ float t[64][65];
  const int tid = threadIdx.x;
  if (tid == 0) sflag = detect_flag((const u16*)x);
  __syncthreads();
  const int fl = sflag;
  const int bid = blockIdx.x;
  if (bid == 1040) {
    if (tid == 0) *flagp = fl;
    return;
  }
  if (bid >= 1024) {  // bias conversion
    if (bid < 1036) {
      const int i = (bid - 1024) * 256 + tid;
      bqf[i] = fl ? bf2f(((const u16*)b_qkv)[i]) : ((const float*)b_qkv)[i];
    } else {
      const int i = (bid - 1036) * 256 + tid;
      bof[i] = fl ? bf2f(((const u16*)b_out)[i]) : ((const float*)b_out)[i];
    }
    return;
  }
  // weight transpose: in [K,N] -> out bf16 [N,K], 64x64 tile via LDS
  const void* in;
  u16* outp;
  int N, bx, by;
  if (bid < 768) { in = w_qkv; outp = wqkvT; N = 3072; bx = bid % 48; by = bid / 48; }
  else { in = w_out; outp = woutT; N = 1024; bx = (bid - 768) % 16; by = (bid - 768) / 16; }
  const int K = 1024;
  const int r = tid >> 4, c4 = tid & 15;
  const int n0 = bx << 6, k0 = by << 6;
#pragma unroll
  for (int i = 0; i < 4; ++i) {
    const int kk = r + i * 16;
    const size_t base = (size_t)(k0 + kk) * N + n0 + c4 * 4;
    if (fl) {
      const uint2 raw = *(const uint2*)((const u16*)in + base);
      t[kk][c4 * 4 + 0] = bf2f((u16)(raw.x & 0xFFFF));
      t[kk][c4 * 4 + 1] = bf2f((u16)(raw.x >> 16));
      t[kk][c4 * 4 + 2] = bf2f((u16)(raw.y & 0xFFFF));
      t[kk][c4 * 4 + 3] = bf2f((u16)(raw.y >> 16));
    } else {
      const float4 v = *(const float4*)((const float*)in + base);
      t[kk][c4 * 4 + 0] = v.x; t[kk][c4 * 4 + 1] = v.y;
      t[kk][c4 * 4 + 2] = v.z; t[kk][c4 * 4 + 3] = v.w;
    }
  }
  __syncthreads();
#pragma unroll
  for (int i = 0; i < 4; ++i) {
    const int nn = r + i * 16;
    uint2 ov;
    ov.x = (u32)f2bf(t[c4 * 4 + 0][nn]) | ((u32)f2bf(t[c4 * 4 + 1][nn]) << 16);
    ov.y = (u32)f2bf(t[c4 * 4 + 2][nn]) | ((u32)f2bf(t[c4 * 4 + 3][nn]) << 16);
    *(uint2*)&outp[(size_t)(n0 + nn) * K + k0 + c4 * 4] = ov;
  }
}

__global__ __launch_bounds__(256)
void cvt_x(const void* __restrict__ in, u16* __restrict__ out,
           const int* __restrict__ flag, size_t eoff4) {
  const size_t i = (size_t)blockIdx.x * 256 + threadIdx.x;
  if (*flag) {
    ((uint2*)out)[i] = ((const uint2*)in)[eoff4 + i];
  } else {
    const float4 v = ((const float4*)in)[eoff4 + i];
    uint2 ov;
    ov.x = (u32)f2bf(v.x) | ((u32)f2bf(v.y) << 16);
    ov.y = (u32)f2bf(v.z) | ((u32)f2bf(v.w) << 16);
    ((uint2*)out)[i] = ov;
  }
}

// ---------------- GEMM: C[M,N] = A[M,K]*BT[N,K]^T + bias ----------------
// 256x128 tile, BK=32, 512 threads (8 waves, 4M x 2N, 64x64 per wave).
// Ring of THREE LDS buffers (72 KiB) -> 2 blocks/CU resident (round-8
// structure, best measured). Prefetch distance 2, counted vmcnt(3).
// Compiler-scheduled ds_read->MFMA (fine-grained lgkmcnt, m97-proven).
// LDS swizzle (0-conflict-PROVEN): src col-granule s ^ ((row>>1)&3), read
// XOR (quad ^ ((l16>>1)&3)); stage dest linear (rule #21).
// V-panel fusion: for BF16 output, tile_n >= 2048 is pure V; epilogue
// writes transposed into vt (eliminates transpose_v kernel).
template <bool BF16_OUT>
__global__ __launch_bounds__(512, 4)
void gemm_bt(const u16* __restrict__ A, const u16* __restrict__ BT,
             const float* __restrict__ bias, void* __restrict__ Cv,
             u16* __restrict__ Vt, int M, int N, int K) {
  constexpr int BK = 32;
  __shared__ __align__(16) u16 ring[3][12288];  // A 8K u16 | B 4K u16 per buf
  const int tid = threadIdx.x;
  const int wid = tid >> 6, lane = tid & 63;
  const int quad = lane >> 4, l16 = lane & 15;

  const int nbx = gridDim.x, nwg = nbx * gridDim.y;
  int bid = blockIdx.y * nbx + blockIdx.x;
  if ((nwg & 7) == 0) bid = (bid & 7) * (nwg >> 3) + (bid >> 3);
  const int tile_n = (bid % nbx) << 7;  // BN=128
  const int tile_m = (bid / nbx) << 8;  // BM=256

  const int wmR = (wid >> 1) << 6;  // 0,64,128,192
  const int wnR = (wid & 1) << 6;   // 0,64

  const int G0 = tid;
  const int rA0 = G0 >> 2, sA0 = ((G0 & 3) ^ ((rA0 >> 1) & 3)) * 8;
  const int G1 = tid + 512;
  const int rA1 = G1 >> 2, sA1 = ((G1 & 3) ^ ((rA1 >> 1) & 3)) * 8;
  const u16* const pA0 = A + (size_t)(tile_m + rA0) * K + sA0;
  const u16* const pA1 = A + (size_t)(tile_m + rA1) * K + sA1;
  const u16* const pB0 = BT + (size_t)(tile_n + rA0) * K + sA0;
  const int dw = wid * 512;  // wave-uniform dst offset (u16)

  const int cA = (quad ^ ((l16 >> 1) & 3)) * 8;

  const int nk = K >> 5;
  f32x4 acc[4][4] = {};

  auto STAGE = [&](int kt, int buf) {
    u16* bp = ring[buf];
    const size_t ko = (size_t)kt * BK;
    gload_lds16(pA0 + ko, bp + dw);
    gload_lds16(pA1 + ko, bp + 4096 + dw);
    gload_lds16(pB0 + ko, bp + 8192 + dw);
  };

  STAGE(0, 0);
  if (nk > 1) STAGE(1, 1);

  int cur = 0;
#pragma unroll 1
  for (int t = 0; t < nk; ++t) {
    if (t + 1 < nk) asm volatile("s_waitcnt vmcnt(3)" ::: "memory");
    else            asm volatile("s_waitcnt vmcnt(0)" ::: "memory");
    __builtin_amdgcn_sched_barrier(0);
    __builtin_amdgcn_s_barrier();  // all waves' stage(t) complete; all reads
                                   // of buf[(t-1)%3] finished (consumed by
                                   // iter t-1's MFMAs, in-order DS retire)
    __builtin_amdgcn_sched_barrier(0);
    int sb = cur + 2; if (sb >= 3) sb -= 3;   // (t+2)%3 == (t-1)%3
    if (t + 2 < nk) STAGE(t + 2, sb);
    const u16* bp = ring[cur];
    bf16x8 af[4], bfr[4];
#pragma unroll
    for (int i = 0; i < 4; ++i)
      af[i] = ld16(&bp[(wmR + i * 16 + l16) * BK + cA]);
#pragma unroll
    for (int j = 0; j < 4; ++j)
      bfr[j] = ld16(&bp[8192 + (wnR + j * 16 + l16) * BK + cA]);
#pragma unroll
    for (int i = 0; i < 4; ++i)
#pragma unroll
      for (int j = 0; j < 4; ++j) acc[i][j] = mfma16(af[i], bfr[j], acc[i][j]);
    cur = (cur + 1 == 3) ? 0 : cur + 1;
  }

  if constexpr (BF16_OUT) {
    if (tile_n >= 2048) {  // pure-V panel: write transposed into Vt
#pragma unroll
      for (int j = 0; j < 4; ++j) {
        const int cv = tile_n - 2048 + wnR + j * 16 + l16;  // h*64+d
        const float bv = bias[2048 + cv];
#pragma unroll
        for (int i = 0; i < 4; ++i) {
          const int rg = tile_m + wmR + i * 16 + quad * 4;  // global s row
          const int b2 = rg >> 11, s = rg & 2047;
          uint2a wv;
          wv.x = cvtpk(acc[i][j][0] + bv, acc[i][j][1] + bv);
          wv.y = cvtpk(acc[i][j][2] + bv, acc[i][j][3] + bv);
          *(uint2a*)&Vt[((size_t)(b2 * 1024 + cv)) * 2048 + s] = wv;
        }
      }
      return;
    }
  }

#pragma unroll
  for (int j = 0; j < 4; ++j) {
    const int cg = tile_n + wnR + j * 16 + l16;
    const float bv = bias[cg];
#pragma unroll
    for (int i = 0; i < 4; ++i) {
      const int rg = tile_m + wmR + i * 16 + quad * 4;
#pragma unroll
      for (int r = 0; r < 4; ++r) {
        const float v = acc[i][j][r] + bv;
        if constexpr (BF16_OUT)
          ((u16*)Cv)[(size_t)(rg + r) * N + cg] = f2bf(v);
        else
          ((float*)Cv)[(size_t)(rg + r) * N + cg] = v;
      }
    }
  }
}

// ---------------- causal flash attention (mfma32, ring-3, 3 blocks/CU) ---
// ROUND-11 CHANGE: one 128-row q-tile per block (grid 16 h x 16 qt x nb =
// 1024 blocks, LPT: qt = 15 - y dispatches heavy tiles first). Ring of
// THREE K/V buffers (48 KiB) + VGPR<=170 (launch_bounds(256,3)) -> 3
// blocks/CU resident: 768 resident + 256 backfill hide the per-iter
// barrier/vmcnt gang stalls that the old 2/CU exact-fit grid exposed
// (round-7 lesson, applied to attn). Pipeline skeleton = the PROVEN
// round-8 gemm ring-3: prefetch distance 2, counted vmcnt(4) (stage = 4
// loads; never 0 mid-loop), stage(kt+2) -> buf[(kt-1)%3] after barrier.
// Compute section byte-identical to the refcheck-proven round-5 kernel:
// swapped 32x32 QK (S^T), in-register P via cvt_pk+permlane32_swap,
// defer-max (THR=8 base-2), l-sum on MFMA pipe, XOR-swizzled LDS.
__global__ __launch_bounds__(256, 3)
void attn_fwd(const u16* __restrict__ qkv, const u16* __restrict__ vt,
              u16* __restrict__ aout) {
  const int h = blockIdx.x, b = blockIdx.z;
  const int qt = 15 - (int)blockIdx.y;  // LPT: heavy first
  const int tid = threadIdx.x, wid = tid >> 6, lane = tid & 63;
  const int l31 = lane & 31, hi = lane >> 5;
  __shared__ __align__(16) u16 ring[3][8192];  // [buf][K:0..4095 | V:4096..]

  const int G0 = wid * 64 + lane, G1 = G0 + 256;
  const int r0 = G0 >> 3, c0 = ((G0 & 7) ^ (r0 & 7)) * 8;
  const int r1 = G1 >> 3, c1 = ((G1 & 7) ^ (r1 & 7)) * 8;
  const int db0 = wid * 512, db1 = 2048 + wid * 512;

  const u16* const kg = qkv + (size_t)(b * SEQ) * 3072 + 1024 + h * 64;
  const u16* const vg = vt + (size_t)((b * 16 + h) * 64) * 2048;

  constexpr float SC = 0.1803368801f;  // (1/8)*log2(e)
  constexpr float THR = 44.3614196f;   // 8 / SC (defer threshold on raw s)

  u32x4 onesu;
  onesu[0] = onesu[1] = onesu[2] = onesu[3] = 0x3F803F80u;  // bf16 1.0 x8
  const bf16x8 ones = __builtin_bit_cast(bf16x8, onesu);

  const int sx = l31 & 7;  // read-side row-XOR

  auto STAGE = [&](int kt, int buf) {
    u16* bp = ring[buf];
    const int kb = kt * 64;
    gload_lds16(kg + (size_t)(kb + r0) * 3072 + c0, bp + db0);
    gload_lds16(kg + (size_t)(kb + r1) * 3072 + c1, bp + db1);
    gload_lds16(vg + (size_t)r0 * 2048 + kb + c0, bp + 4096 + db0);
    gload_lds16(vg + (size_t)r1 * 2048 + kb + c1, bp + 4096 + db1);
  };

  const int q0w = qt * 128 + wid * 32;
  const int qrow = q0w + l31;
  bf16x8 qf[4];  // B-operand: Q[qrow][dblk*16 + hi*8 .. +7]
#pragma unroll
  for (int d = 0; d < 4; ++d)
    qf[d] = ld16(&qkv[(size_t)(b * SEQ + qrow) * 3072 + h * 64 + d * 16 + hi * 8]);
  f32x16 o0 = {}, o1 = {}, lacc = {};
  float m_r = -1e30f, ms = -1.8e29f;

  const int last = 2 * qt + 1;
  STAGE(0, 0);
  if (last >= 1) STAGE(1, 1);

  int cur = 0;
#pragma unroll 1
  for (int kt = 0; kt <= last; ++kt) {
    // stage(kt) retired for this wave (stage kt+1's 4 loads may remain)
    if (kt + 1 <= last) asm volatile("s_waitcnt vmcnt(4)" ::: "memory");
    else                asm volatile("s_waitcnt vmcnt(0)" ::: "memory");
    __builtin_amdgcn_sched_barrier(0);
    __builtin_amdgcn_s_barrier();  // all waves' stage(kt) complete; all
                                   // reads of buf[(kt-1)%3] drained
    __builtin_amdgcn_sched_barrier(0);
    int sb = cur + 2; if (sb >= 3) sb -= 3;  // (kt+2)%3 == (kt-1)%3
    if (kt + 2 <= last) STAGE(kt + 2, sb);
    const int kb = kt * 64;
    if (kb <= q0w + 31) {  // wave-uniform: tile not fully masked
      const u16* const lKc = ring[cur];
      const u16* const lVc = ring[cur] + 4096;
      f32x16 s0 = {}, s1 = {};
      bf16x8 kf0[4], kf1[4];
#pragma unroll
      for (int d = 0; d < 4; ++d) {
        kf0[d] = ld16(&lKc[l31 * 64 + (((d * 2 + hi) ^ sx)) * 8]);
        kf1[d] = ld16(&lKc[(32 + l31) * 64 + (((d * 2 + hi) ^ sx)) * 8]);
      }
      __builtin_amdgcn_s_setprio(1);
#pragma unroll
      for (int d = 0; d < 4; ++d) s0 = mfma32(kf0[d], qf[d], s0);
#pragma unroll
      for (int d = 0; d < 4; ++d) s1 = mfma32(kf1[d], qf[d], s1);
      __builtin_amdgcn_s_setprio(0);
      bf16x8 vf[2][2][2];  // [kh][j][dh]
#pragma unroll
      for (int kh = 0; kh < 2; ++kh)
#pragma unroll
        for (int j = 0; j < 2; ++j)
#pragma unroll
          for (int dh = 0; dh < 2; ++dh)
            vf[kh][j][dh] = ld16(
                &lVc[(dh * 32 + l31) * 64 + (((kh * 4 + j * 2 + hi) ^ sx)) * 8]);
      if (kb + 63 > q0w) {  // wave-uniform: diagonal masking needed
        const int rel = qrow - kb - 4 * hi;
#pragma unroll
        for (int i = 0; i < 16; ++i) {
          const int kc = (i & 3) + 8 * (i >> 2);
          if (kc > rel) s0[i] = -1e30f;
          if (kc + 32 > rel) s1[i] = -1e30f;
        }
      }
      float pm = fmaxf(fmaxf(s0[0], s0[1]), s0[2]);
      pm = fmaxf(fmaxf(pm, s0[3]), s0[4]);
      pm = fmaxf(fmaxf(pm, s0[5]), s0[6]);
      pm = fmaxf(fmaxf(pm, s0[7]), s0[8]);
      pm = fmaxf(fmaxf(pm, s0[9]), s0[10]);
      pm = fmaxf(fmaxf(pm, s0[11]), s0[12]);
      pm = fmaxf(fmaxf(pm, s0[13]), s0[14]);
      pm = fmaxf(fmaxf(pm, s0[15]), s1[0]);
      pm = fmaxf(fmaxf(pm, s1[1]), s1[2]);
      pm = fmaxf(fmaxf(pm, s1[3]), s1[4]);
      pm = fmaxf(fmaxf(pm, s1[5]), s1[6]);
      pm = fmaxf(fmaxf(pm, s1[7]), s1[8]);
      pm = fmaxf(fmaxf(pm, s1[9]), s1[10]);
      pm = fmaxf(fmaxf(pm, s1[11]), s1[12]);
      pm = fmaxf(fmaxf(pm, s1[13]), s1[14]);
      pm = fmaxf(pm, s1[15]);
      if (__any(pm > m_r + THR)) {
        const float mm = fmaxf(pm, __shfl_xor(pm, 32));
        const float mn = fmaxf(m_r, mm);
        const float al = exp2f((m_r - mn) * SC);
#pragma unroll
        for (int i = 0; i < 16; ++i) {
          o0[i] *= al; o1[i] *= al; lacc[i] *= al;
        }
        m_r = mn;
        ms = mn * SC;
      }
#pragma unroll
      for (int i = 0; i < 16; ++i) {
        s0[i] = exp2f(fmaf(s0[i], SC, -ms));
        s1[i] = exp2f(fmaf(s1[i], SC, -ms));
      }
      u32 t0 = cvtpk(s0[0], s0[1]), t1 = cvtpk(s0[2], s0[3]);
      u32 t2 = cvtpk(s0[4], s0[5]), t3 = cvtpk(s0[6], s0[7]);
      u32 t4 = cvtpk(s0[8], s0[9]), t5 = cvtpk(s0[10], s0[11]);
      u32 t6 = cvtpk(s0[12], s0[13]), t7 = cvtpk(s0[14], s0[15]);
      plane32_swap(t0, t2); plane32_swap(t1, t3);
      plane32_swap(t4, t6); plane32_swap(t5, t7);
      u32x4 w00, w01;
      w00[0] = t0; w00[1] = t1; w00[2] = t2; w00[3] = t3;
      w01[0] = t4; w01[1] = t5; w01[2] = t6; w01[3] = t7;
      u32 u0 = cvtpk(s1[0], s1[1]), u1 = cvtpk(s1[2], s1[3]);
      u32 u2 = cvtpk(s1[4], s1[5]), u3 = cvtpk(s1[6], s1[7]);
      u32 u4 = cvtpk(s1[8], s1[9]), u5 = cvtpk(s1[10], s1[11]);
      u32 u6 = cvtpk(s1[12], s1[13]), u7 = cvtpk(s1[14], s1[15]);
      plane32_swap(u0, u2); plane32_swap(u1, u3);
      plane32_swap(u4, u6); plane32_swap(u5, u7);
      u32x4 w10, w11;
      w10[0] = u0; w10[1] = u1; w10[2] = u2; w10[3] = u3;
      w11[0] = u4; w11[1] = u5; w11[2] = u6; w11[3] = u7;
      const bf16x8 pb00 = __builtin_bit_cast(bf16x8, w00);
      const bf16x8 pb01 = __builtin_bit_cast(bf16x8, w01);
      const bf16x8 pb10 = __builtin_bit_cast(bf16x8, w10);
      const bf16x8 pb11 = __builtin_bit_cast(bf16x8, w11);
      __builtin_amdgcn_s_setprio(1);
      o0 = mfma32(vf[0][0][0], pb00, o0);
      o1 = mfma32(vf[0][0][1], pb00, o1);
      lacc = mfma32(ones, pb00, lacc);
      o0 = mfma32(vf[0][1][0], pb01, o0);
      o1 = mfma32(vf[0][1][1], pb01, o1);
      lacc = mfma32(ones, pb01, lacc);
      o0 = mfma32(vf[1][0][0], pb10, o0);
      o1 = mfma32(vf[1][0][1], pb10, o1);
      lacc = mfma32(ones, pb10, lacc);
      o0 = mfma32(vf[1][1][0], pb11, o0);
      o1 = mfma32(vf[1][1][1], pb11, o1);
      lacc = mfma32(ones, pb11, lacc);
      __builtin_amdgcn_s_setprio(0);
    }
    cur = (cur + 1 == 3) ? 0 : cur + 1;
  }
  // epilogue: o[dh][reg] = O^T[d = dh*32+(reg&3)+8*(reg>>2)+4*hi][q = l31]
  const float inv = 1.0f / lacc[0];
  u16* const orow = &aout[(size_t)(b * SEQ + qrow) * 1024 + h * 64];
#pragma unroll
  for (int t = 0; t < 4; ++t) {
    const int d0 = 8 * t + 4 * hi;
    uint2a wv;
    wv.x = cvtpk(o0[4 * t] * inv, o0[4 * t + 1] * inv);
    wv.y = cvtpk(o0[4 * t + 2] * inv, o0[4 * t + 3] * inv);
    *(uint2a*)&orow[d0] = wv;
    wv.x = cvtpk(o1[4 * t] * inv, o1[4 * t + 1] * inv);
    wv.y = cvtpk(o1[4 * t + 2] * inv, o1[4 * t + 3] * inv);
    *(uint2a*)&orow[32 + d0] = wv;
  }
}

extern "C" void kernel_launch(void* const* d_in, const int* in_sizes, int n_in,
                              void* d_out, int out_size, void* d_ws, size_t ws_size,
                              hipStream_t stream) {
  const void* x     = d_in[0];
  const void* w_qkv = d_in[1];
  const void* b_qkv = d_in[2];
  const void* w_out = d_in[3];
  const void* b_out = d_in[4];
  float* out = (float*)d_out;  // reference output dtype is fp32

  // common prefix
  float* bqf   = (float*)d_ws;                      // [3072] fp32
  float* bof   = bqf + 3072;                        // [1024] fp32
  int*   flag  = (int*)(bof + 1024);                // [4]
  u16*   wqkvT = (u16*)(flag + 4);                  // [3072,1024]
  u16*   woutT = wqkvT + (size_t)3072 * 1024;       // [1024,1024]
  u16*   xb    = woutT + (size_t)1024 * 1024;       // [M,1024]

  prep_all<<<dim3(1041), dim3(256), 0, stream>>>(
      x, w_qkv, b_qkv, w_out, b_out, wqkvT, woutT, bqf, bof, flag);

  // full-batch path needs 92,291,088 B of ws; fall back to per-batch otherwise.
  const size_t FULL_WS = 92291088;  // constant across calls -> graph-safe branch
  if (ws_size >= FULL_WS) {
    u16* qkv = xb  + (size_t)8192 * 1024;           // [8192,3072]
    u16* vt  = qkv + (size_t)8192 * 3072;           // [64,64,2048]
    cvt_x<<<dim3(8192), dim3(256), 0, stream>>>(x, xb, flag, 0);
    gemm_bt<true ><<<dim3(24, 32), dim3(512), 0, stream>>>(xb, wqkvT, bqf, qkv,
                                                           vt, 8192, 3072, 1024);
    attn_fwd<<<dim3(16, 16, 4), dim3(256), 0, stream>>>(qkv, vt, xb);
    gemm_bt<false><<<dim3(8, 32), dim3(512), 0, stream>>>(xb, woutT, bof, out,
                                                          vt, 8192, 1024, 1024);
  } else {
    u16* qkvb = xb   + (size_t)2048 * 1024;         // [2048,3072]
    u16* vtb  = qkvb + (size_t)2048 * 3072;         // [16,64,2048]
    for (int b = 0; b < 4; ++b) {
      const size_t eoff4 = (size_t)b * 2048 * 1024 / 4;
      cvt_x<<<dim3(2048), dim3(256), 0, stream>>>(x, xb, flag, eoff4);
      gemm_bt<true ><<<dim3(24, 8), dim3(512), 0, stream>>>(xb, wqkvT, bqf, qkvb,
                                                            vtb, 2048, 3072, 1024);
      attn_fwd<<<dim3(16, 16, 1), dim3(256), 0, stream>>>(qkvb, vtb, xb);
      gemm_bt<false><<<dim3(8, 8), dim3(512), 0, stream>>>(
          xb, woutT, bof, out + (size_t)b * 2048 * 1024, vtb, 2048, 1024, 1024);
    }
  }
}

// Round 12
// 273.294 us; speedup vs baseline: 1.0665x; 1.0665x over previous
//
#include <hip/hip_runtime.h>

typedef unsigned short u16;
typedef unsigned int u32;
using f32x4 = __attribute__((ext_vector_type(4))) float;
using f32x16 = __attribute__((ext_vector_type(16))) float;
using u32x4 = __attribute__((ext_vector_type(4))) u32;
typedef u32x4 __attribute__((may_alias)) u32x4a;  // TBAA-safe 16B vector
typedef uint2 __attribute__((may_alias)) uint2a;  // TBAA-safe 8B vector
using bf16x8 = __attribute__((ext_vector_type(8))) __bf16;

#define SEQ 2048  // per batch

// fp32 -> bf16 round-to-nearest-even
__device__ __forceinline__ u16 f2bf(float f) {
  union { float f; u32 u; } c; c.f = f;
  return (u16)((c.u + 0x7fffu + ((c.u >> 16) & 1u)) >> 16);
}
__device__ __forceinline__ float bf2f(u16 h) {
  union { u32 u; float f; } c; c.u = ((u32)h) << 16;
  return c.f;
}
__device__ __forceinline__ bf16x8 ld16(const u16* p) {
  return __builtin_bit_cast(bf16x8, *(const u32x4a*)p);
}
__device__ __forceinline__ f32x4 mfma16(bf16x8 a, bf16x8 b, f32x4 c) {
  return __builtin_amdgcn_mfma_f32_16x16x32_bf16(a, b, c, 0, 0, 0);
}
__device__ __forceinline__ f32x16 mfma32(bf16x8 a, bf16x8 b, f32x16 c) {
  return __builtin_amdgcn_mfma_f32_32x32x16_bf16(a, b, c, 0, 0, 0);
}
// async global->LDS, 16B/lane; LDS dest = wave-uniform base + lane*16
__device__ __forceinline__ void gload_lds16(const u16* g, u16* l) {
  __builtin_amdgcn_global_load_lds(
      (const __attribute__((address_space(1))) void*)g,
      (__attribute__((address_space(3))) void*)l, 16, 0, 0);
}
// pack 2 fp32 -> 1 u32 of 2 bf16 (RNE); no builtin on gfx950
__device__ __forceinline__ u32 cvtpk(float lo, float hi) {
  u32 r;
  asm("v_cvt_pk_bf16_f32 %0, %1, %2" : "=v"(r) : "v"(lo), "v"(hi));
  return r;
}
// new_a = [a.lanes0-31 | b.lanes0-31], new_b = [a.lanes32-63 | b.lanes32-63]
__device__ __forceinline__ void plane32_swap(u32& a, u32& b) {
  asm("v_permlane32_swap_b32 %0, %1" : "+v"(a), "+v"(b));
}
// dtype sniff: bf16 iff exponent bits of x[2i] cluster near 127
__device__ __forceinline__ int detect_flag(const u16* x) {
  int cnt = 0;
  for (int i = 0; i < 32; ++i) {
    const int e = (x[2 * i] >> 7) & 0xFF;
    cnt += (e >= 100 && e <= 140) ? 1 : 0;
  }
  return (cnt >= 20) ? 1 : 0;
}

// ---------------- fused prep: cvt_x + detect + bias cvt + W transposes ---
// grid (cvt_blocks + 1041) x 256. [0,cvt_blocks): x -> bf16 copy slice.
// Then: 768 w_qkv 64x64 tiles; 256 w_out tiles; 12 bqf; 4 bof; last block
// persists flag (for the per-batch fallback cvt_x). Every block computes
// the dtype flag inline (lane 0 scan of x[0..63] + LDS broadcast) -- no
// device-wide serialization on a 1-block detect kernel, no flag read dep.
__global__ __launch_bounds__(256)
void prep_all(const void* __restrict__ x, const void* __restrict__ w_qkv,
              const void* __restrict__ b_qkv, const void* __restrict__ w_out,
              const void* __restrict__ b_out, u16* __restrict__ wqkvT,
              u16* __restrict__ woutT, float* __restrict__ bqf,
              float* __restrict__ bof, int* __restrict__ flagp,
              u16* __restrict__ xb, int cvt_blocks) {
  __shared__ int sflag;
  __shared__ float t[64][65];
  const int tid = threadIdx.x;
  if (tid == 0) sflag = detect_flag((const u16*)x);
  __syncthreads();
  const int fl = sflag;
  if ((int)blockIdx.x < cvt_blocks) {  // x -> bf16 (or copy) slice
    const size_t i = (size_t)blockIdx.x * 256 + tid;
    if (fl) {
      ((uint2*)xb)[i] = ((const uint2*)x)[i];
    } else {
      const float4 v = ((const float4*)x)[i];
      uint2 ov;
      ov.x = (u32)f2bf(v.x) | ((u32)f2bf(v.y) << 16);
      ov.y = (u32)f2bf(v.z) | ((u32)f2bf(v.w) << 16);
      ((uint2*)xb)[i] = ov;
    }
    return;
  }
  const int bid = blockIdx.x - cvt_blocks;
  if (bid == 1040) {
    if (tid == 0) *flagp = fl;
    return;
  }
  if (bid >= 1024) {  // bias conversion
    if (bid < 1036) {
      const int i = (bid - 1024) * 256 + tid;
      bqf[i] = fl ? bf2f(((const u16*)b_qkv)[i]) : ((const float*)b_qkv)[i];
    } else {
      const int i = (bid - 1036) * 256 + tid;
      bof[i] = fl ? bf2f(((const u16*)b_out)[i]) : ((const float*)b_out)[i];
    }
    return;
  }
  // weight transpose: in [K,N] -> out bf16 [N,K], 64x64 tile via LDS
  const void* in;
  u16* outp;
  int N, bx, by;
  if (bid < 768) { in = w_qkv; outp = wqkvT; N = 3072; bx = bid % 48; by = bid / 48; }
  else { in = w_out; outp = woutT; N = 1024; bx = (bid - 768) % 16; by = (bid - 768) / 16; }
  const int K = 1024;
  const int r = tid >> 4, c4 = tid & 15;
  const int n0 = bx << 6, k0 = by << 6;
#pragma unroll
  for (int i = 0; i < 4; ++i) {
    const int kk = r + i * 16;
    const size_t base = (size_t)(k0 + kk) * N + n0 + c4 * 4;
    if (fl) {
      const uint2 raw = *(const uint2*)((const u16*)in + base);
      t[kk][c4 * 4 + 0] = bf2f((u16)(raw.x & 0xFFFF));
      t[kk][c4 * 4 + 1] = bf2f((u16)(raw.x >> 16));
      t[kk][c4 * 4 + 2] = bf2f((u16)(raw.y & 0xFFFF));
      t[kk][c4 * 4 + 3] = bf2f((u16)(raw.y >> 16));
    } else {
      const float4 v = *(const float4*)((const float*)in + base);
      t[kk][c4 * 4 + 0] = v.x; t[kk][c4 * 4 + 1] = v.y;
      t[kk][c4 * 4 + 2] = v.z; t[kk][c4 * 4 + 3] = v.w;
    }
  }
  __syncthreads();
#pragma unroll
  for (int i = 0; i < 4; ++i) {
    const int nn = r + i * 16;
    uint2 ov;
    ov.x = (u32)f2bf(t[c4 * 4 + 0][nn]) | ((u32)f2bf(t[c4 * 4 + 1][nn]) << 16);
    ov.y = (u32)f2bf(t[c4 * 4 + 2][nn]) | ((u32)f2bf(t[c4 * 4 + 3][nn]) << 16);
    *(uint2*)&outp[(size_t)(n0 + nn) * K + k0 + c4 * 4] = ov;
  }
}

__global__ __launch_bounds__(256)
void cvt_x(const void* __restrict__ in, u16* __restrict__ out,
           const int* __restrict__ flag, size_t eoff4) {
  const size_t i = (size_t)blockIdx.x * 256 + threadIdx.x;
  if (*flag) {
    ((uint2*)out)[i] = ((const uint2*)in)[eoff4 + i];
  } else {
    const float4 v = ((const float4*)in)[eoff4 + i];
    uint2 ov;
    ov.x = (u32)f2bf(v.x) | ((u32)f2bf(v.y) << 16);
    ov.y = (u32)f2bf(v.z) | ((u32)f2bf(v.w) << 16);
    ((uint2*)out)[i] = ov;
  }
}

// ---------------- GEMM: C[M,N] = A[M,K]*BT[N,K]^T + bias ----------------
// 256x128 tile, BK=32, 512 threads (8 waves, 4M x 2N, 64x64 per wave).
// Ring of THREE LDS buffers (72 KiB) -> 2 blocks/CU resident (round-8
// structure, best measured). Prefetch distance 2, counted vmcnt(3).
// Compiler-scheduled ds_read->MFMA (fine-grained lgkmcnt, m97-proven).
// LDS swizzle (0-conflict-PROVEN): src col-granule s ^ ((row>>1)&3), read
// XOR (quad ^ ((l16>>1)&3)); stage dest linear (rule #21).
// V-panel fusion: for BF16 output, tile_n >= 2048 is pure V; epilogue
// writes transposed into vt (eliminates transpose_v kernel).
template <bool BF16_OUT>
__global__ __launch_bounds__(512, 4)
void gemm_bt(const u16* __restrict__ A, const u16* __restrict__ BT,
             const float* __restrict__ bias, void* __restrict__ Cv,
             u16* __restrict__ Vt, int M, int N, int K) {
  constexpr int BK = 32;
  __shared__ __align__(16) u16 ring[3][12288];  // A 8K u16 | B 4K u16 per buf
  const int tid = threadIdx.x;
  const int wid = tid >> 6, lane = tid & 63;
  const int quad = lane >> 4, l16 = lane & 15;

  const int nbx = gridDim.x, nwg = nbx * gridDim.y;
  int bid = blockIdx.y * nbx + blockIdx.x;
  if ((nwg & 7) == 0) bid = (bid & 7) * (nwg >> 3) + (bid >> 3);
  const int tile_n = (bid % nbx) << 7;  // BN=128
  const int tile_m = (bid / nbx) << 8;  // BM=256

  const int wmR = (wid >> 1) << 6;  // 0,64,128,192
  const int wnR = (wid & 1) << 6;   // 0,64

  const int G0 = tid;
  const int rA0 = G0 >> 2, sA0 = ((G0 & 3) ^ ((rA0 >> 1) & 3)) * 8;
  const int G1 = tid + 512;
  const int rA1 = G1 >> 2, sA1 = ((G1 & 3) ^ ((rA1 >> 1) & 3)) * 8;
  const u16* const pA0 = A + (size_t)(tile_m + rA0) * K + sA0;
  const u16* const pA1 = A + (size_t)(tile_m + rA1) * K + sA1;
  const u16* const pB0 = BT + (size_t)(tile_n + rA0) * K + sA0;
  const int dw = wid * 512;  // wave-uniform dst offset (u16)

  const int cA = (quad ^ ((l16 >> 1) & 3)) * 8;

  const int nk = K >> 5;
  f32x4 acc[4][4] = {};

  auto STAGE = [&](int kt, int buf) {
    u16* bp = ring[buf];
    const size_t ko = (size_t)kt * BK;
    gload_lds16(pA0 + ko, bp + dw);
    gload_lds16(pA1 + ko, bp + 4096 + dw);
    gload_lds16(pB0 + ko, bp + 8192 + dw);
  };

  STAGE(0, 0);
  if (nk > 1) STAGE(1, 1);

  int cur = 0;
#pragma unroll 1
  for (int t = 0; t < nk; ++t) {
    if (t + 1 < nk) asm volatile("s_waitcnt vmcnt(3)" ::: "memory");
    else            asm volatile("s_waitcnt vmcnt(0)" ::: "memory");
    __builtin_amdgcn_sched_barrier(0);
    __builtin_amdgcn_s_barrier();  // all waves' stage(t) complete; all reads
                                   // of buf[(t-1)%3] finished (consumed by
                                   // iter t-1's MFMAs, in-order DS retire)
    __builtin_amdgcn_sched_barrier(0);
    int sb = cur + 2; if (sb >= 3) sb -= 3;   // (t+2)%3 == (t-1)%3
    if (t + 2 < nk) STAGE(t + 2, sb);
    const u16* bp = ring[cur];
    bf16x8 af[4], bfr[4];
#pragma unroll
    for (int i = 0; i < 4; ++i)
      af[i] = ld16(&bp[(wmR + i * 16 + l16) * BK + cA]);
#pragma unroll
    for (int j = 0; j < 4; ++j)
      bfr[j] = ld16(&bp[8192 + (wnR + j * 16 + l16) * BK + cA]);
#pragma unroll
    for (int i = 0; i < 4; ++i)
#pragma unroll
      for (int j = 0; j < 4; ++j) acc[i][j] = mfma16(af[i], bfr[j], acc[i][j]);
    cur = (cur + 1 == 3) ? 0 : cur + 1;
  }

  if constexpr (BF16_OUT) {
    if (tile_n >= 2048) {  // pure-V panel: write transposed into Vt
#pragma unroll
      for (int j = 0; j < 4; ++j) {
        const int cv = tile_n - 2048 + wnR + j * 16 + l16;  // h*64+d
        const float bv = bias[2048 + cv];
#pragma unroll
        for (int i = 0; i < 4; ++i) {
          const int rg = tile_m + wmR + i * 16 + quad * 4;  // global s row
          const int b2 = rg >> 11, s = rg & 2047;
          uint2a wv;
          wv.x = cvtpk(acc[i][j][0] + bv, acc[i][j][1] + bv);
          wv.y = cvtpk(acc[i][j][2] + bv, acc[i][j][3] + bv);
          *(uint2a*)&Vt[((size_t)(b2 * 1024 + cv)) * 2048 + s] = wv;
        }
      }
      return;
    }
  }

#pragma unroll
  for (int j = 0; j < 4; ++j) {
    const int cg = tile_n + wnR + j * 16 + l16;
    const float bv = bias[cg];
#pragma unroll
    for (int i = 0; i < 4; ++i) {
      const int rg = tile_m + wmR + i * 16 + quad * 4;
#pragma unroll
      for (int r = 0; r < 4; ++r) {
        const float v = acc[i][j][r] + bv;
        if constexpr (BF16_OUT)
          ((u16*)Cv)[(size_t)(rg + r) * N + cg] = f2bf(v);
        else
          ((float*)Cv)[(size_t)(rg + r) * N + cg] = v;
      }
    }
  }
}

// ---------------- causal flash attention (mfma32, ring-4 pipeline) -------
// ROUND-12: reverted to the round-10 structure (best measured; round-11's
// one-tile-per-block LPT variant regressed 80->99us from tail imbalance).
// grid (16 h, 8 pair-slots, nb). Block y does 128-row q-tiles {15-y, y}:
// uniform 36 k-iterations -> load-balanced by construction. Ring-4 K/V
// LDS (64 KB, 2 blocks/CU), prefetch distance 3, counted vmcnt(8/4/0).
// Swapped 32x32 QK (S^T), in-register P via cvt_pk+permlane32_swap,
// defer-max (THR=8 base-2), l-sum on MFMA pipe, XOR-swizzled LDS.
__global__ __launch_bounds__(256, 2)
void attn_fwd(const u16* __restrict__ qkv, const u16* __restrict__ vt,
              u16* __restrict__ aout) {
  const int h = blockIdx.x, b = blockIdx.z;
  const int tid = threadIdx.x, wid = tid >> 6, lane = tid & 63;
  const int l31 = lane & 31, hi = lane >> 5;
  __shared__ __align__(16) u16 ring[4][8192];  // [buf][K:0..4095 | V:4096..]

  const int G0 = wid * 64 + lane, G1 = G0 + 256;
  const int r0 = G0 >> 3, c0 = ((G0 & 7) ^ (r0 & 7)) * 8;
  const int r1 = G1 >> 3, c1 = ((G1 & 7) ^ (r1 & 7)) * 8;
  const int db0 = wid * 512, db1 = 2048 + wid * 512;

  const u16* const kg = qkv + (size_t)(b * SEQ) * 3072 + 1024 + h * 64;
  const u16* const vg = vt + (size_t)((b * 16 + h) * 64) * 2048;

  constexpr float SC = 0.1803368801f;  // (1/8)*log2(e)
  constexpr float THR = 44.3614196f;   // 8 / SC (defer threshold on raw s)

  u32x4 onesu;
  onesu[0] = onesu[1] = onesu[2] = onesu[3] = 0x3F803F80u;  // bf16 1.0 x8
  const bf16x8 ones = __builtin_bit_cast(bf16x8, onesu);

  const int sx = l31 & 7;  // read-side row-XOR

  auto STAGE = [&](int kt) {
    u16* bp = ring[kt & 3];
    const int kb = kt * 64;
    gload_lds16(kg + (size_t)(kb + r0) * 3072 + c0, bp + db0);
    gload_lds16(kg + (size_t)(kb + r1) * 3072 + c1, bp + db1);
    gload_lds16(vg + (size_t)r0 * 2048 + kb + c0, bp + 4096 + db0);
    gload_lds16(vg + (size_t)r1 * 2048 + kb + c1, bp + 4096 + db1);
  };

#pragma unroll 1
  for (int pass = 0; pass < 2; ++pass) {
    const int qt = pass ? (int)blockIdx.y : 15 - (int)blockIdx.y;
    const int q0w = qt * 128 + wid * 32;
    const int qrow = q0w + l31;
    bf16x8 qf[4];  // B-operand: Q[qrow][dblk*16 + hi*8 .. +7]
#pragma unroll
    for (int d = 0; d < 4; ++d)
      qf[d] = ld16(&qkv[(size_t)(b * SEQ + qrow) * 3072 + h * 64 + d * 16 + hi * 8]);
    f32x16 o0 = {}, o1 = {}, lacc = {};
    float m_r = -1e30f, ms = -1.8e29f;

    const int last = 2 * qt + 1;
    __syncthreads();  // buffer handoff across passes (drains everything)
    STAGE(0);
    if (last >= 1) STAGE(1);
    if (last >= 2) STAGE(2);

#pragma unroll 1
    for (int kt = 0; kt <= last; ++kt) {
      const int rem = last - kt;
      if (rem >= 2)      asm volatile("s_waitcnt vmcnt(8)" ::: "memory");
      else if (rem == 1) asm volatile("s_waitcnt vmcnt(4)" ::: "memory");
      else               asm volatile("s_waitcnt vmcnt(0)" ::: "memory");
      __builtin_amdgcn_sched_barrier(0);
      __builtin_amdgcn_s_barrier();
      __builtin_amdgcn_sched_barrier(0);
      if (kt + 3 <= last) STAGE(kt + 3);
      const int kb = kt * 64;
      if (kb <= q0w + 31) {  // wave-uniform: tile not fully masked
        const u16* const lKc = ring[kt & 3];
        const u16* const lVc = ring[kt & 3] + 4096;
        f32x16 s0 = {}, s1 = {};
        bf16x8 kf0[4], kf1[4];
#pragma unroll
        for (int d = 0; d < 4; ++d) {
          kf0[d] = ld16(&lKc[l31 * 64 + (((d * 2 + hi) ^ sx)) * 8]);
          kf1[d] = ld16(&lKc[(32 + l31) * 64 + (((d * 2 + hi) ^ sx)) * 8]);
        }
        __builtin_amdgcn_s_setprio(1);
#pragma unroll
        for (int d = 0; d < 4; ++d) s0 = mfma32(kf0[d], qf[d], s0);
#pragma unroll
        for (int d = 0; d < 4; ++d) s1 = mfma32(kf1[d], qf[d], s1);
        __builtin_amdgcn_s_setprio(0);
        bf16x8 vf[2][2][2];  // [kh][j][dh]
#pragma unroll
        for (int kh = 0; kh < 2; ++kh)
#pragma unroll
          for (int j = 0; j < 2; ++j)
#pragma unroll
            for (int dh = 0; dh < 2; ++dh)
              vf[kh][j][dh] = ld16(
                  &lVc[(dh * 32 + l31) * 64 + (((kh * 4 + j * 2 + hi) ^ sx)) * 8]);
        if (kb + 63 > q0w) {  // wave-uniform: diagonal masking needed
          const int rel = qrow - kb - 4 * hi;
#pragma unroll
          for (int i = 0; i < 16; ++i) {
            const int kc = (i & 3) + 8 * (i >> 2);
            if (kc > rel) s0[i] = -1e30f;
            if (kc + 32 > rel) s1[i] = -1e30f;
          }
        }
        float pm = fmaxf(fmaxf(s0[0], s0[1]), s0[2]);
        pm = fmaxf(fmaxf(pm, s0[3]), s0[4]);
        pm = fmaxf(fmaxf(pm, s0[5]), s0[6]);
        pm = fmaxf(fmaxf(pm, s0[7]), s0[8]);
        pm = fmaxf(fmaxf(pm, s0[9]), s0[10]);
        pm = fmaxf(fmaxf(pm, s0[11]), s0[12]);
        pm = fmaxf(fmaxf(pm, s0[13]), s0[14]);
        pm = fmaxf(fmaxf(pm, s0[15]), s1[0]);
        pm = fmaxf(fmaxf(pm, s1[1]), s1[2]);
        pm = fmaxf(fmaxf(pm, s1[3]), s1[4]);
        pm = fmaxf(fmaxf(pm, s1[5]), s1[6]);
        pm = fmaxf(fmaxf(pm, s1[7]), s1[8]);
        pm = fmaxf(fmaxf(pm, s1[9]), s1[10]);
        pm = fmaxf(fmaxf(pm, s1[11]), s1[12]);
        pm = fmaxf(fmaxf(pm, s1[13]), s1[14]);
        pm = fmaxf(pm, s1[15]);
        if (__any(pm > m_r + THR)) {
          const float mm = fmaxf(pm, __shfl_xor(pm, 32));
          const float mn = fmaxf(m_r, mm);
          const float al = exp2f((m_r - mn) * SC);
#pragma unroll
          for (int i = 0; i < 16; ++i) {
            o0[i] *= al; o1[i] *= al; lacc[i] *= al;
          }
          m_r = mn;
          ms = mn * SC;
        }
#pragma unroll
        for (int i = 0; i < 16; ++i) {
          s0[i] = exp2f(fmaf(s0[i], SC, -ms));
          s1[i] = exp2f(fmaf(s1[i], SC, -ms));
        }
        u32 t0 = cvtpk(s0[0], s0[1]), t1 = cvtpk(s0[2], s0[3]);
        u32 t2 = cvtpk(s0[4], s0[5]), t3 = cvtpk(s0[6], s0[7]);
        u32 t4 = cvtpk(s0[8], s0[9]), t5 = cvtpk(s0[10], s0[11]);
        u32 t6 = cvtpk(s0[12], s0[13]), t7 = cvtpk(s0[14], s0[15]);
        plane32_swap(t0, t2); plane32_swap(t1, t3);
        plane32_swap(t4, t6); plane32_swap(t5, t7);
        u32x4 w00, w01;
        w00[0] = t0; w00[1] = t1; w00[2] = t2; w00[3] = t3;
        w01[0] = t4; w01[1] = t5; w01[2] = t6; w01[3] = t7;
        u32 u0 = cvtpk(s1[0], s1[1]), u1 = cvtpk(s1[2], s1[3]);
        u32 u2 = cvtpk(s1[4], s1[5]), u3 = cvtpk(s1[6], s1[7]);
        u32 u4 = cvtpk(s1[8], s1[9]), u5 = cvtpk(s1[10], s1[11]);
        u32 u6 = cvtpk(s1[12], s1[13]), u7 = cvtpk(s1[14], s1[15]);
        plane32_swap(u0, u2); plane32_swap(u1, u3);
        plane32_swap(u4, u6); plane32_swap(u5, u7);
        u32x4 w10, w11;
        w10[0] = u0; w10[1] = u1; w10[2] = u2; w10[3] = u3;
        w11[0] = u4; w11[1] = u5; w11[2] = u6; w11[3] = u7;
        const bf16x8 pb00 = __builtin_bit_cast(bf16x8, w00);
        const bf16x8 pb01 = __builtin_bit_cast(bf16x8, w01);
        const bf16x8 pb10 = __builtin_bit_cast(bf16x8, w10);
        const bf16x8 pb11 = __builtin_bit_cast(bf16x8, w11);
        __builtin_amdgcn_s_setprio(1);
        o0 = mfma32(vf[0][0][0], pb00, o0);
        o1 = mfma32(vf[0][0][1], pb00, o1);
        lacc = mfma32(ones, pb00, lacc);
        o0 = mfma32(vf[0][1][0], pb01, o0);
        o1 = mfma32(vf[0][1][1], pb01, o1);
        lacc = mfma32(ones, pb01, lacc);
        o0 = mfma32(vf[1][0][0], pb10, o0);
        o1 = mfma32(vf[1][0][1], pb10, o1);
        lacc = mfma32(ones, pb10, lacc);
        o0 = mfma32(vf[1][1][0], pb11, o0);
        o1 = mfma32(vf[1][1][1], pb11, o1);
        lacc = mfma32(ones, pb11, lacc);
        __builtin_amdgcn_s_setprio(0);
      }
    }
    const float inv = 1.0f / lacc[0];
    u16* const orow = &aout[(size_t)(b * SEQ + qrow) * 1024 + h * 64];
#pragma unroll
    for (int t = 0; t < 4; ++t) {
      const int d0 = 8 * t + 4 * hi;
      uint2a wv;
      wv.x = cvtpk(o0[4 * t] * inv, o0[4 * t + 1] * inv);
      wv.y = cvtpk(o0[4 * t + 2] * inv, o0[4 * t + 3] * inv);
      *(uint2a*)&orow[d0] = wv;
      wv.x = cvtpk(o1[4 * t] * inv, o1[4 * t + 1] * inv);
      wv.y = cvtpk(o1[4 * t + 2] * inv, o1[4 * t + 3] * inv);
      *(uint2a*)&orow[32 + d0] = wv;
    }
  }
}

extern "C" void kernel_launch(void* const* d_in, const int* in_sizes, int n_in,
                              void* d_out, int out_size, void* d_ws, size_t ws_size,
                              hipStream_t stream) {
  const void* x     = d_in[0];
  const void* w_qkv = d_in[1];
  const void* b_qkv = d_in[2];
  const void* w_out = d_in[3];
  const void* b_out = d_in[4];
  float* out = (float*)d_out;  // reference output dtype is fp32

  // common prefix
  float* bqf   = (float*)d_ws;                      // [3072] fp32
  float* bof   = bqf + 3072;                        // [1024] fp32
  int*   flag  = (int*)(bof + 1024);                // [4]
  u16*   wqkvT = (u16*)(flag + 4);                  // [3072,1024]
  u16*   woutT = wqkvT + (size_t)3072 * 1024;       // [1024,1024]
  u16*   xb    = woutT + (size_t)1024 * 1024;       // [M,1024]

  // full-batch path needs 92,291,088 B of ws; fall back to per-batch otherwise.
  const size_t FULL_WS = 92291088;  // constant across calls -> graph-safe branch
  if (ws_size >= FULL_WS) {
    u16* qkv = xb  + (size_t)8192 * 1024;           // [8192,3072]
    u16* vt  = qkv + (size_t)8192 * 3072;           // [64,64,2048]
    // fused prep: cvt_x (8192 blocks) + transposes/bias/flag (1041 blocks)
    prep_all<<<dim3(8192 + 1041), dim3(256), 0, stream>>>(
        x, w_qkv, b_qkv, w_out, b_out, wqkvT, woutT, bqf, bof, flag, xb, 8192);
    gemm_bt<true ><<<dim3(24, 32), dim3(512), 0, stream>>>(xb, wqkvT, bqf, qkv,
                                                           vt, 8192, 3072, 1024);
    attn_fwd<<<dim3(16, 8, 4), dim3(256), 0, stream>>>(qkv, vt, xb);
    gemm_bt<false><<<dim3(8, 32), dim3(512), 0, stream>>>(xb, woutT, bof, out,
                                                          vt, 8192, 1024, 1024);
  } else {
    u16* qkvb = xb   + (size_t)2048 * 1024;         // [2048,3072]
    u16* vtb  = qkvb + (size_t)2048 * 3072;         // [16,64,2048]
    prep_all<<<dim3(1041), dim3(256), 0, stream>>>(
        x, w_qkv, b_qkv, w_out, b_out, wqkvT, woutT, bqf, bof, flag, xb, 0);
    for (int b = 0; b < 4; ++b) {
      const size_t eoff4 = (size_t)b * 2048 * 1024 / 4;
      cvt_x<<<dim3(2048), dim3(256), 0, stream>>>(x, xb, flag, eoff4);
      gemm_bt<true ><<<dim3(24, 8), dim3(512), 0, stream>>>(xb, wqkvT, bqf, qkvb,
                                                            vtb, 2048, 3072, 1024);
      attn_fwd<<<dim3(16, 8, 1), dim3(256), 0, stream>>>(qkvb, vtb, xb);
      gemm_bt<false><<<dim3(8, 8), dim3(512), 0, stream>>>(
          xb, woutT, bof, out + (size_t)b * 2048 * 1024, vtb, 2048, 1024, 1024);
    }
  }
}